// Round 5
// baseline (821.772 us; speedup 1.0000x reference)
//
#include <hip/hip_runtime.h>
#include <hip/hip_bf16.h>

typedef __hip_bfloat16 bf16;
typedef __attribute__((ext_vector_type(8))) __bf16 bf16x8;
typedef __attribute__((ext_vector_type(4))) float f32x4;

#define HW 16384

static __device__ __forceinline__ float b2f(bf16 v) { return __bfloat162float(v); }
static __device__ __forceinline__ bf16 f2b(float v) { return __float2bfloat16(v); }
static __device__ __forceinline__ unsigned short f2bu(float v) {
    union { bf16 b; unsigned short u; } c; c.b = f2b(v); return c.u;
}
static __device__ __forceinline__ float blo(unsigned int w) { return __uint_as_float(w << 16); }
static __device__ __forceinline__ float bhi(unsigned int w) { return __uint_as_float(w & 0xffff0000u); }

// pack B[k][n], B[k+1][n] -> one dword (even k in low half) for the bf16x8 frag
static __device__ __forceinline__ unsigned int loadpair(const float* p, int rs) {
    return (unsigned int)f2bu(p[0]) | ((unsigned int)f2bu(p[rs]) << 16);
}
static __device__ __forceinline__ unsigned int loadpair(const bf16* p, int rs) {
    union { bf16 b; unsigned short u; } a, c; a.b = p[0]; c.b = p[rs];
    return (unsigned int)a.u | ((unsigned int)c.u << 16);
}
static __device__ __forceinline__ void stf(float* p, float v) { *p = v; }
static __device__ __forceinline__ void stf(bf16* p, float v) { *p = f2b(v); }

// ============ K1/K7: fused GEMM  Y[b][m][n] = W[m][k=192] @ Bsrc[b][k][n] ====
// LDS-free. Block = 64-n strip x full M. Wave owns 16 n-columns; B fragments
// (k-pair packed dwords) live in 24 VGPRs for the whole kernel; A fragments
// read per 64-m chunk from the L2-resident weight matrix.
template <typename TB, typename TY>
__global__ __launch_bounds__(256) void gemm_fused(
    const float* __restrict__ Wsrc, long wstride, int M,
    const TB* __restrict__ Bsrc, long bstride,
    TY* __restrict__ Y)
{
    const int n0 = blockIdx.x * 64, b = blockIdx.y;
    const float* Wb = Wsrc + (size_t)b * wstride;
    const TB* Bb = Bsrc + (size_t)b * bstride;
    TY* Yb = Y + (size_t)b * M * HW;

    const int lane = threadIdx.x & 63, wave = threadIdx.x >> 6;
    const int r16 = lane & 15, quad = lane >> 4;
    const int n = n0 + wave * 16 + r16;   // this lane's output column

    // B fragments: breg[kc][j] = B[kc*32 + quad*8 + j][n], j=0..7
    bf16x8 breg[6];
#pragma unroll
    for (int kc = 0; kc < 6; kc++) {
        union { unsigned int u[4]; bf16x8 v; } pk;
#pragma unroll
        for (int i = 0; i < 4; i++) {
            int k = kc * 32 + quad * 8 + 2 * i;
            pk.u[i] = loadpair(Bb + ((size_t)k << 14) + n, HW);
        }
        breg[kc] = pk.v;
    }

    for (int m0 = 0; m0 < M; m0 += 64) {
        f32x4 acc[4];
#pragma unroll
        for (int i = 0; i < 4; i++) acc[i] = (f32x4){0.f, 0.f, 0.f, 0.f};
#pragma unroll
        for (int kc = 0; kc < 6; kc++) {
#pragma unroll
            for (int i = 0; i < 4; i++) {
                const float* ap = Wb + (size_t)(m0 + i * 16 + r16) * 192 + kc * 32 + quad * 8;
                float4 x0 = *(const float4*)ap;
                float4 x1 = *(const float4*)(ap + 4);
                union { unsigned int u[4]; bf16x8 v; } af;
                af.u[0] = (unsigned)f2bu(x0.x) | ((unsigned)f2bu(x0.y) << 16);
                af.u[1] = (unsigned)f2bu(x0.z) | ((unsigned)f2bu(x0.w) << 16);
                af.u[2] = (unsigned)f2bu(x1.x) | ((unsigned)f2bu(x1.y) << 16);
                af.u[3] = (unsigned)f2bu(x1.z) | ((unsigned)f2bu(x1.w) << 16);
                acc[i] = __builtin_amdgcn_mfma_f32_16x16x32_bf16(af.v, breg[kc], acc[i], 0, 0, 0);
            }
        }
        // C/D: col = lane&15 (n), row = quad*4 + reg  [verified m89/m91]
#pragma unroll
        for (int i = 0; i < 4; i++) {
            int gr = m0 + i * 16 + quad * 4;
#pragma unroll
            for (int r = 0; r < 4; r++)
                stf(Yb + ((size_t)(gr + r) << 14) + n, acc[i][r]);
        }
    }
}

// ============ K2: depthwise 3x3 + fused sum-of-squares for q/k planes =======
__global__ __launch_bounds__(256) void dwconv3x3(
    const bf16* __restrict__ in, const float* __restrict__ wdw,
    bf16* __restrict__ out, float* __restrict__ sq)
{
    const int plane = blockIdx.x >> 2;          // b*576 + c
    const int ybase = (blockIdx.x & 3) << 5;    // 0,32,64,96
    const int c = plane % 576;
    const bf16* ip = in + ((size_t)plane << 14);

    __shared__ unsigned short Ls[34][128];
    __shared__ float red[4];

    for (int i = threadIdx.x; i < 34 * 16; i += 256) {
        int r = i >> 4, cx = i & 15;
        int y = ybase - 1 + r;
        uint4 v = make_uint4(0u, 0u, 0u, 0u);
        if (y >= 0 && y < 128) v = ((const uint4*)(ip + ((size_t)y << 7)))[cx];
        ((uint4*)Ls[r])[cx] = v;
    }

    float w[9];
#pragma unroll
    for (int i = 0; i < 9; i++) w[i] = wdw[c * 9 + i];

    __syncthreads();

    const int lr = threadIdx.x >> 3;
    const int c0 = (threadIdx.x & 7) << 4;

    float row[3][18];
#pragma unroll
    for (int r3 = 0; r3 < 3; r3++) {
        int rr = lr + r3;
        row[r3][0]  = c0 ? __uint_as_float((unsigned int)Ls[rr][c0 - 1] << 16) : 0.f;
        row[r3][17] = (c0 + 16 < 128) ? __uint_as_float((unsigned int)Ls[rr][c0 + 16] << 16) : 0.f;
        const uint4* rp = (const uint4*)&Ls[rr][c0];
        uint4 p0 = rp[0], p1 = rp[1];
        row[r3][1] = blo(p0.x); row[r3][2] = bhi(p0.x);
        row[r3][3] = blo(p0.y); row[r3][4] = bhi(p0.y);
        row[r3][5] = blo(p0.z); row[r3][6] = bhi(p0.z);
        row[r3][7] = blo(p0.w); row[r3][8] = bhi(p0.w);
        row[r3][9]  = blo(p1.x); row[r3][10] = bhi(p1.x);
        row[r3][11] = blo(p1.y); row[r3][12] = bhi(p1.y);
        row[r3][13] = blo(p1.z); row[r3][14] = bhi(p1.z);
        row[r3][15] = blo(p1.w); row[r3][16] = bhi(p1.w);
    }

    float ss = 0.f;
    union { unsigned short s[16]; uint4 v[2]; } o;
#pragma unroll
    for (int j = 0; j < 16; j++) {
        float s = 0.f;
#pragma unroll
        for (int r3 = 0; r3 < 3; r3++)
            s += w[r3 * 3 + 0] * row[r3][j] + w[r3 * 3 + 1] * row[r3][j + 1]
               + w[r3 * 3 + 2] * row[r3][j + 2];
        ss += s * s;
        o.s[j] = f2bu(s);
    }
    uint4* op = (uint4*)(out + ((size_t)plane << 14) + ((size_t)(ybase + lr) << 7) + c0);
    op[0] = o.v[0];
    op[1] = o.v[1];

    if (c < 384) {   // q or k plane: accumulate ||row||^2
#pragma unroll
        for (int off = 32; off; off >>= 1) ss += __shfl_down(ss, off);
        if ((threadIdx.x & 63) == 0) red[threadIdx.x >> 6] = ss;
        __syncthreads();
        if (threadIdx.x == 0) {
            int b = plane / 576;
            int rowi = (c < 192) ? (b * 192 + c) : (1536 + b * 192 + (c - 192));
            atomicAdd(&sq[rowi], red[0] + red[1] + red[2] + red[3]);
        }
    }
}

// ============ K4: LDS-free MFMA dots S[bh][c][d] = sum_n q[c][n] k[d][n] ====
__global__ __launch_bounds__(256) void attn_dots(
    const bf16* __restrict__ qkv, float* __restrict__ attn)
{
    const int bh = blockIdx.y, b = bh >> 2, h = bh & 3;
    const int wave = threadIdx.x >> 6, lane = threadIdx.x & 63;
    const int r16 = lane & 15, quad = lane >> 4;
    const bf16* q  = qkv + ((size_t)(b * 576 + h * 48) << 14);
    const bf16* kp = qkv + ((size_t)(b * 576 + 192 + h * 48) << 14);
    const int nbase = (blockIdx.x * 4 + wave) * 512;

    f32x4 acc[3][3];
#pragma unroll
    for (int i = 0; i < 3; i++)
#pragma unroll
        for (int j = 0; j < 3; j++) acc[i][j] = (f32x4){0.f, 0.f, 0.f, 0.f};

    for (int t = 0; t < 16; t++) {
        const int nb = nbase + t * 32 + quad * 8;
        bf16x8 qa[3], ka[3];
#pragma unroll
        for (int i = 0; i < 3; i++) {
            qa[i] = *(const bf16x8*)(q  + ((size_t)(i * 16 + r16) << 14) + nb);
            ka[i] = *(const bf16x8*)(kp + ((size_t)(i * 16 + r16) << 14) + nb);
        }
#pragma unroll
        for (int i = 0; i < 3; i++)
#pragma unroll
            for (int j = 0; j < 3; j++)
                acc[i][j] = __builtin_amdgcn_mfma_f32_16x16x32_bf16(
                    qa[i], ka[j], acc[i][j], 0, 0, 0);
    }

    float* ap = attn + (size_t)bh * 2304;
#pragma unroll
    for (int i = 0; i < 3; i++)
#pragma unroll
        for (int j = 0; j < 3; j++) {
            int c = i * 16 + quad * 4;
            int d = j * 16 + r16;
#pragma unroll
            for (int r = 0; r < 4; r++)
                atomicAdd(&ap[(c + r) * 48 + d], acc[i][j][r]);
        }
}

// ============ K5: normalize by L2 norms & temperature, softmax over d =======
__global__ __launch_bounds__(64) void softmax48(
    float* __restrict__ attn, const float* __restrict__ sq,
    const float* __restrict__ temp)
{
    int bh = blockIdx.x, b = bh >> 2, h = bh & 3;
    int c = threadIdx.x;
    __shared__ float ik[48];
    if (c < 48) ik[c] = 1.0f / fmaxf(sqrtf(sq[1536 + b * 192 + h * 48 + c]), 1e-12f);
    __syncthreads();
    if (c >= 48) return;
    float t = temp[h];
    float iq = 1.0f / fmaxf(sqrtf(sq[b * 192 + h * 48 + c]), 1e-12f);
    float* row = attn + (size_t)bh * 2304 + c * 48;

    float v[48];
    float mx = -1e30f;
#pragma unroll
    for (int d = 0; d < 48; d++) {
        v[d] = row[d] * iq * ik[d] * t;
        mx = fmaxf(mx, v[d]);
    }
    float s = 0.f;
#pragma unroll
    for (int d = 0; d < 48; d++) {
        v[d] = expf(v[d] - mx);
        s += v[d];
    }
    float inv = 1.0f / s;
#pragma unroll
    for (int d = 0; d < 48; d++) row[d] = v[d] * inv;
}

// ============ K6: P[b][m][h*48+d] = sum_cc proj_w[m][h*48+cc] A[bh][cc][d] ==
// (out = proj @ (A @ v) == (proj (.) A) @ v — fold proj into A per head)
__global__ __launch_bounds__(256) void pmat(
    const float* __restrict__ proj_w, const float* __restrict__ attn,
    float* __restrict__ P)
{
    const int bh = blockIdx.x, b = bh >> 2, h = bh & 3;
    __shared__ float A[48][49];
    for (int i = threadIdx.x; i < 2304; i += 256)
        A[i / 48][i % 48] = attn[(size_t)bh * 2304 + i];
    __syncthreads();
    const int m = threadIdx.x;
    if (m >= 192) return;
    float w[48];
    const float4* pw = (const float4*)(proj_w + m * 192 + h * 48);
#pragma unroll
    for (int i = 0; i < 12; i++) {
        float4 v = pw[i];
        w[i * 4] = v.x; w[i * 4 + 1] = v.y; w[i * 4 + 2] = v.z; w[i * 4 + 3] = v.w;
    }
    float* Pr = P + (size_t)(b * 192 + m) * 192 + h * 48;
#pragma unroll 4
    for (int d = 0; d < 48; d++) {
        float s = 0.f;
#pragma unroll
        for (int cc = 0; cc < 48; cc++) s += w[cc] * A[cc][d];
        Pr[d] = s;
    }
}

// ============================================================================
extern "C" void kernel_launch(void* const* d_in, const int* in_sizes, int n_in,
                              void* d_out, int out_size, void* d_ws, size_t ws_size,
                              hipStream_t stream)
{
    const float* x      = (const float*)d_in[0];
    const float* qkv_w  = (const float*)d_in[1];
    const float* dw_w   = (const float*)d_in[2];
    const float* proj_w = (const float*)d_in[3];
    const float* temp   = (const float*)d_in[4];
    float* out = (float*)d_out;

    char* ws = (char*)d_ws;
    const size_t Q = (size_t)8 * 576 * HW * sizeof(bf16);     // 151 MB
    bf16*  qkv0 = (bf16*)ws;          // K1 out; dead after dwconv
    bf16*  qkv1 = (bf16*)(ws + Q);    // post-dw qkv
    float* attn = (float*)(ws + 2 * Q);                 // 294,912 B
    float* sq   = (float*)(ws + 2 * Q + 294912);        // 12,288 B
    float* P    = (float*)ws;         // 1.18 MB, overlays dead qkv0 region

    // 0) zero attn + sq (contiguous)
    hipMemsetAsync(attn, 0, 294912 + 12288, stream);
    // 1) qkv 1x1 conv, fused transpose: qkv0[b][576][n] = qkv_w @ x[b]
    gemm_fused<float, bf16><<<dim3(256, 8), 256, 0, stream>>>(
        qkv_w, 0L, 576, x, (long)192 * HW, qkv0);
    // 2) depthwise 3x3 + fused sum-of-squares
    dwconv3x3<<<dim3(8 * 576 * 4), 256, 0, stream>>>(qkv0, dw_w, qkv1, sq);
    // 3) attention dots (MFMA, LDS-free, f32 atomics)
    attn_dots<<<dim3(8, 32), 256, 0, stream>>>(qkv1, attn);
    // 4) normalize + softmax
    softmax48<<<dim3(32), 64, 0, stream>>>(attn, sq, temp);
    // 5) fold proj into attention: P[b] (writes over dead qkv0 region)
    pmat<<<dim3(32), 256, 0, stream>>>(proj_w, attn, P);
    // 6) out[b][192][n] = P[b] @ v[b]  (v = planes 384..575 of qkv1)
    gemm_fused<bf16, float><<<dim3(256, 8), 256, 0, stream>>>(
        P, (long)192 * 192, 192, qkv1 + (size_t)384 * HW, (long)576 * HW, out);
}

// Round 6
// 582.768 us; speedup vs baseline: 1.4101x; 1.4101x over previous
//
#include <hip/hip_runtime.h>
#include <hip/hip_bf16.h>

typedef __hip_bfloat16 bf16;
typedef __attribute__((ext_vector_type(8))) __bf16 bf16x8;
typedef __attribute__((ext_vector_type(4))) float f32x4;

#define HW 16384

static __device__ __forceinline__ float b2f(bf16 v) { return __bfloat162float(v); }
static __device__ __forceinline__ bf16 f2b(float v) { return __float2bfloat16(v); }
static __device__ __forceinline__ unsigned short f2bu(float v) {
    union { bf16 b; unsigned short u; } c; c.b = f2b(v); return c.u;
}
static __device__ __forceinline__ float blo(unsigned int w) { return __uint_as_float(w << 16); }
static __device__ __forceinline__ float bhi(unsigned int w) { return __uint_as_float(w & 0xffff0000u); }
static __device__ __forceinline__ void stf(float* p, float v) { *p = v; }
static __device__ __forceinline__ void stf(bf16* p, float v) { *p = f2b(v); }

// pack B[k][n], B[k+1][n] (stride rs) -> one dword (even k low)
static __device__ __forceinline__ unsigned int loadpair(const bf16* p, int rs) {
    union { bf16 b; unsigned short u; } a, c; a.b = p[0]; c.b = p[rs];
    return (unsigned int)a.u | ((unsigned int)c.u << 16);
}

// ============ W cast: f32 [m][k] -> bf16 [m][k] (576x192 = 110592 elems) ====
__global__ __launch_bounds__(256) void wcast(
    const float* __restrict__ w, bf16* __restrict__ wb, int n4)
{
    int i = blockIdx.x * 256 + threadIdx.x;
    if (i >= n4) return;
    float4 v = ((const float4*)w)[i];
    union { unsigned short s[4]; uint2 u; } o;
    o.s[0] = f2bu(v.x); o.s[1] = f2bu(v.y); o.s[2] = f2bu(v.z); o.s[3] = f2bu(v.w);
    ((uint2*)wb)[i] = o.u;
}

// ============ T0: transpose + cast  x[b][192][HW] f32 -> xT[b][HW][192] bf16
__global__ __launch_bounds__(256) void transpose_cast(
    const float* __restrict__ x, bf16* __restrict__ xT)
{
    __shared__ float T[64][65];
    const int k0 = blockIdx.x * 64, n0 = blockIdx.y * 64, b = blockIdx.z;
    const float* xb = x + ((size_t)(b * 192 + k0) << 14) + n0;

    for (int s = threadIdx.x; s < 64 * 16; s += 256) {
        int k = s >> 4, n4 = (s & 15) * 4;
        float4 v = *(const float4*)(xb + ((size_t)k << 14) + n4);
        T[k][n4] = v.x; T[k][n4 + 1] = v.y; T[k][n4 + 2] = v.z; T[k][n4 + 3] = v.w;
    }
    __syncthreads();

    bf16* xo = xT + ((size_t)b << 14) * 192 + (size_t)n0 * 192 + k0;
    for (int s = threadIdx.x; s < 64 * 8; s += 256) {
        int n = s >> 3, k8 = (s & 7) * 8;
        union { unsigned short u[8]; uint4 v; } o;
#pragma unroll
        for (int j = 0; j < 8; j++) o.u[j] = f2bu(T[k8 + j][n]);
        *(uint4*)(xo + (size_t)n * 192 + k8) = o.v;
    }
}

// ============ K1/K7: register GEMM  Y[b][m][n] = Wb[m][k=192] @ B[b] ========
// LDS-free, barrier-free. Block = 64-n strip x full M; wave owns 16 n.
// B-frags (24 VGPRs) loaded once per block: BNK ? from Bt[n][k] (b128 direct)
//                                               : from B[k][n] (paired scalar).
// A-frags: 12 independent b128 loads per 32-m step from bf16 W (L2-resident).
template <typename TY, bool BNK>
__global__ __launch_bounds__(256) void gemm_reg(
    const bf16* __restrict__ Wsrc, long wstride, int M,
    const bf16* __restrict__ Bsrc, long bstride,
    TY* __restrict__ Y)
{
    const int n0 = blockIdx.x * 64, b = blockIdx.y;
    const bf16* Wb = Wsrc + (size_t)b * wstride;
    const bf16* Bb = Bsrc + (size_t)b * bstride;
    TY* Yb = Y + (size_t)b * M * HW;

    const int lane = threadIdx.x & 63, wave = threadIdx.x >> 6;
    const int r16 = lane & 15, quad = lane >> 4;
    const int n = n0 + wave * 16 + r16;

    bf16x8 breg[6];
    if (BNK) {
#pragma unroll
        for (int kc = 0; kc < 6; kc++)
            breg[kc] = *(const bf16x8*)(Bb + (size_t)n * 192 + kc * 32 + quad * 8);
    } else {
#pragma unroll
        for (int kc = 0; kc < 6; kc++) {
            union { unsigned int u[4]; bf16x8 v; } pk;
#pragma unroll
            for (int i = 0; i < 4; i++) {
                int k = kc * 32 + quad * 8 + 2 * i;
                pk.u[i] = loadpair(Bb + ((size_t)k << 14) + n, HW);
            }
            breg[kc] = pk.v;
        }
    }

    for (int mt = 0; mt < M; mt += 32) {
        bf16x8 af[2][6];
#pragma unroll
        for (int i = 0; i < 2; i++)
#pragma unroll
            for (int kc = 0; kc < 6; kc++)
                af[i][kc] = *(const bf16x8*)(
                    Wb + (size_t)(mt + i * 16 + r16) * 192 + kc * 32 + quad * 8);

        f32x4 acc[2];
#pragma unroll
        for (int i = 0; i < 2; i++) acc[i] = (f32x4){0.f, 0.f, 0.f, 0.f};
#pragma unroll
        for (int kc = 0; kc < 6; kc++) {
            acc[0] = __builtin_amdgcn_mfma_f32_16x16x32_bf16(af[0][kc], breg[kc], acc[0], 0, 0, 0);
            acc[1] = __builtin_amdgcn_mfma_f32_16x16x32_bf16(af[1][kc], breg[kc], acc[1], 0, 0, 0);
        }
        // C/D: col = r16 (n), row = quad*4 + reg  [verified m89/m91]
#pragma unroll
        for (int i = 0; i < 2; i++) {
            int gr = mt + i * 16 + quad * 4;
#pragma unroll
            for (int r = 0; r < 4; r++)
                stf(Yb + ((size_t)(gr + r) << 14) + n, acc[i][r]);
        }
    }
}

// ============ K2: depthwise 3x3 + fused sum-of-squares for q/k planes =======
__global__ __launch_bounds__(256) void dwconv3x3(
    const bf16* __restrict__ in, const float* __restrict__ wdw,
    bf16* __restrict__ out, float* __restrict__ sq)
{
    const int plane = blockIdx.x >> 2;          // b*576 + c
    const int ybase = (blockIdx.x & 3) << 5;    // 0,32,64,96
    const int c = plane % 576;
    const bf16* ip = in + ((size_t)plane << 14);

    __shared__ unsigned short Ls[34][128];
    __shared__ float red[4];

    for (int i = threadIdx.x; i < 34 * 16; i += 256) {
        int r = i >> 4, cx = i & 15;
        int y = ybase - 1 + r;
        uint4 v = make_uint4(0u, 0u, 0u, 0u);
        if (y >= 0 && y < 128) v = ((const uint4*)(ip + ((size_t)y << 7)))[cx];
        ((uint4*)Ls[r])[cx] = v;
    }

    float w[9];
#pragma unroll
    for (int i = 0; i < 9; i++) w[i] = wdw[c * 9 + i];

    __syncthreads();

    const int lr = threadIdx.x >> 3;
    const int c0 = (threadIdx.x & 7) << 4;

    float row[3][18];
#pragma unroll
    for (int r3 = 0; r3 < 3; r3++) {
        int rr = lr + r3;
        row[r3][0]  = c0 ? __uint_as_float((unsigned int)Ls[rr][c0 - 1] << 16) : 0.f;
        row[r3][17] = (c0 + 16 < 128) ? __uint_as_float((unsigned int)Ls[rr][c0 + 16] << 16) : 0.f;
        const uint4* rp = (const uint4*)&Ls[rr][c0];
        uint4 p0 = rp[0], p1 = rp[1];
        row[r3][1] = blo(p0.x); row[r3][2] = bhi(p0.x);
        row[r3][3] = blo(p0.y); row[r3][4] = bhi(p0.y);
        row[r3][5] = blo(p0.z); row[r3][6] = bhi(p0.z);
        row[r3][7] = blo(p0.w); row[r3][8] = bhi(p0.w);
        row[r3][9]  = blo(p1.x); row[r3][10] = bhi(p1.x);
        row[r3][11] = blo(p1.y); row[r3][12] = bhi(p1.y);
        row[r3][13] = blo(p1.z); row[r3][14] = bhi(p1.z);
        row[r3][15] = blo(p1.w); row[r3][16] = bhi(p1.w);
    }

    float ss = 0.f;
    union { unsigned short s[16]; uint4 v[2]; } o;
#pragma unroll
    for (int j = 0; j < 16; j++) {
        float s = 0.f;
#pragma unroll
        for (int r3 = 0; r3 < 3; r3++)
            s += w[r3 * 3 + 0] * row[r3][j] + w[r3 * 3 + 1] * row[r3][j + 1]
               + w[r3 * 3 + 2] * row[r3][j + 2];
        ss += s * s;
        o.s[j] = f2bu(s);
    }
    uint4* op = (uint4*)(out + ((size_t)plane << 14) + ((size_t)(ybase + lr) << 7) + c0);
    op[0] = o.v[0];
    op[1] = o.v[1];

    if (c < 384) {
#pragma unroll
        for (int off = 32; off; off >>= 1) ss += __shfl_down(ss, off);
        if ((threadIdx.x & 63) == 0) red[threadIdx.x >> 6] = ss;
        __syncthreads();
        if (threadIdx.x == 0) {
            int b = plane / 576;
            int rowi = (c < 192) ? (b * 192 + c) : (1536 + b * 192 + (c - 192));
            atomicAdd(&sq[rowi], red[0] + red[1] + red[2] + red[3]);
        }
    }
}

// ============ K4: LDS-free MFMA dots S[bh][c][d] = sum_n q[c][n] k[d][n] ====
__global__ __launch_bounds__(256) void attn_dots(
    const bf16* __restrict__ qkv, float* __restrict__ attn)
{
    const int bh = blockIdx.y, b = bh >> 2, h = bh & 3;
    const int wave = threadIdx.x >> 6, lane = threadIdx.x & 63;
    const int r16 = lane & 15, quad = lane >> 4;
    const bf16* q  = qkv + ((size_t)(b * 576 + h * 48) << 14);
    const bf16* kp = qkv + ((size_t)(b * 576 + 192 + h * 48) << 14);
    const int nbase = (blockIdx.x * 4 + wave) * 512;

    f32x4 acc[3][3];
#pragma unroll
    for (int i = 0; i < 3; i++)
#pragma unroll
        for (int j = 0; j < 3; j++) acc[i][j] = (f32x4){0.f, 0.f, 0.f, 0.f};

    for (int t = 0; t < 16; t++) {
        const int nb = nbase + t * 32 + quad * 8;
        bf16x8 qa[3], ka[3];
#pragma unroll
        for (int i = 0; i < 3; i++) {
            qa[i] = *(const bf16x8*)(q  + ((size_t)(i * 16 + r16) << 14) + nb);
            ka[i] = *(const bf16x8*)(kp + ((size_t)(i * 16 + r16) << 14) + nb);
        }
#pragma unroll
        for (int i = 0; i < 3; i++)
#pragma unroll
            for (int j = 0; j < 3; j++)
                acc[i][j] = __builtin_amdgcn_mfma_f32_16x16x32_bf16(
                    qa[i], ka[j], acc[i][j], 0, 0, 0);
    }

    float* ap = attn + (size_t)bh * 2304;
#pragma unroll
    for (int i = 0; i < 3; i++)
#pragma unroll
        for (int j = 0; j < 3; j++) {
            int c = i * 16 + quad * 4;
            int d = j * 16 + r16;
#pragma unroll
            for (int r = 0; r < 4; r++)
                atomicAdd(&ap[(c + r) * 48 + d], acc[i][j][r]);
        }
}

// ============ K5: normalize by L2 norms & temperature, softmax over d =======
__global__ __launch_bounds__(64) void softmax48(
    float* __restrict__ attn, const float* __restrict__ sq,
    const float* __restrict__ temp)
{
    int bh = blockIdx.x, b = bh >> 2, h = bh & 3;
    int c = threadIdx.x;
    __shared__ float ik[48];
    if (c < 48) ik[c] = 1.0f / fmaxf(sqrtf(sq[1536 + b * 192 + h * 48 + c]), 1e-12f);
    __syncthreads();
    if (c >= 48) return;
    float t = temp[h];
    float iq = 1.0f / fmaxf(sqrtf(sq[b * 192 + h * 48 + c]), 1e-12f);
    float* row = attn + (size_t)bh * 2304 + c * 48;

    float v[48];
    float mx = -1e30f;
#pragma unroll
    for (int d = 0; d < 48; d++) {
        v[d] = row[d] * iq * ik[d] * t;
        mx = fmaxf(mx, v[d]);
    }
    float s = 0.f;
#pragma unroll
    for (int d = 0; d < 48; d++) {
        v[d] = expf(v[d] - mx);
        s += v[d];
    }
    float inv = 1.0f / s;
#pragma unroll
    for (int d = 0; d < 48; d++) row[d] = v[d] * inv;
}

// ============ K6: P[b][m][h*48+d] = sum_cc proj_w[m][h*48+cc] A[bh][cc][d] ==
// out = proj @ (A @ v) == (proj (.) A) @ v; P stored bf16 k-contig for K7.
__global__ __launch_bounds__(256) void pmat(
    const float* __restrict__ proj_w, const float* __restrict__ attn,
    bf16* __restrict__ P)
{
    const int bh = blockIdx.x, b = bh >> 2, h = bh & 3;
    __shared__ float A[48][49];
    for (int i = threadIdx.x; i < 2304; i += 256)
        A[i / 48][i % 48] = attn[(size_t)bh * 2304 + i];
    __syncthreads();
    const int m = threadIdx.x;
    if (m >= 192) return;
    float w[48];
    const float4* pw = (const float4*)(proj_w + m * 192 + h * 48);
#pragma unroll
    for (int i = 0; i < 12; i++) {
        float4 v = pw[i];
        w[i * 4] = v.x; w[i * 4 + 1] = v.y; w[i * 4 + 2] = v.z; w[i * 4 + 3] = v.w;
    }
    bf16* Pr = P + (size_t)(b * 192 + m) * 192 + h * 48;
#pragma unroll 4
    for (int d = 0; d < 48; d++) {
        float s = 0.f;
#pragma unroll
        for (int cc = 0; cc < 48; cc++) s += w[cc] * A[cc][d];
        Pr[d] = f2b(s);
    }
}

// ============================================================================
extern "C" void kernel_launch(void* const* d_in, const int* in_sizes, int n_in,
                              void* d_out, int out_size, void* d_ws, size_t ws_size,
                              hipStream_t stream)
{
    const float* x      = (const float*)d_in[0];
    const float* qkv_w  = (const float*)d_in[1];
    const float* dw_w   = (const float*)d_in[2];
    const float* proj_w = (const float*)d_in[3];
    const float* temp   = (const float*)d_in[4];
    float* out = (float*)d_out;

    char* ws = (char*)d_ws;
    const size_t Q = (size_t)8 * 576 * HW * sizeof(bf16);     // 150,994,944 B
    bf16*  qkv0 = (bf16*)ws;          // K1 out; dead after dwconv
    bf16*  qkv1 = (bf16*)(ws + Q);    // xT first, then post-dw qkv
    bf16*  xT   = qkv1;               // 100.7 MB; dead after K1
    bf16*  Wbf  = (bf16*)(ws + Q + (size_t)110 * 1024 * 1024); // 221 KB, in
                                      // xT-region tail (dead after K1)
    float* attn = (float*)(ws + 2 * Q);                 // 294,912 B
    float* sq   = (float*)(ws + 2 * Q + 294912);        // 12,288 B
    bf16*  Pbf  = (bf16*)ws;          // 590 KB, overlays dead qkv0 region

    // 0) zero attn + sq
    hipMemsetAsync(attn, 0, 294912 + 12288, stream);
    // 0b) cast qkv weight to bf16 (576*192 / 4 = 27648 float4s)
    wcast<<<dim3(108), 256, 0, stream>>>(qkv_w, Wbf, 27648);
    // 0c) transpose + cast x -> xT [b][n][k]
    transpose_cast<<<dim3(3, 256, 8), 256, 0, stream>>>(x, xT);
    // 1) qkv 1x1 conv: qkv0[b][576][n] = Wbf @ xT
    gemm_reg<bf16, true><<<dim3(256, 8), 256, 0, stream>>>(
        Wbf, 0L, 576, xT, (long)HW * 192, qkv0);
    // 2) depthwise 3x3 + fused sum-of-squares (overwrites xT/Wbf region)
    dwconv3x3<<<dim3(8 * 576 * 4), 256, 0, stream>>>(qkv0, dw_w, qkv1, sq);
    // 3) attention dots (MFMA, LDS-free, f32 atomics)
    attn_dots<<<dim3(8, 32), 256, 0, stream>>>(qkv1, attn);
    // 4) normalize + softmax
    softmax48<<<dim3(32), 64, 0, stream>>>(attn, sq, temp);
    // 5) fold proj into attention -> Pbf (over dead qkv0)
    pmat<<<dim3(32), 256, 0, stream>>>(proj_w, attn, Pbf);
    // 6) out[b][192][n] = Pbf[b] @ v[b]  (v = planes 384..575 of qkv1)
    gemm_reg<float, false><<<dim3(256, 8), 256, 0, stream>>>(
        Pbf, (long)192 * 192, 192, qkv1 + (size_t)384 * HW, (long)576 * HW, out);
}